// Round 2
// baseline (1080.509 us; speedup 1.0000x reference)
//
#include <hip/hip_runtime.h>
#include <hip/hip_bf16.h>

#define D 128
#define SCAN_CHUNK 1024

// ---------------------------------------------------------------------------
// K1: y = x @ W^T + b  (into ws), x2 = x @ Wself^T + bself (into d_out)
// 256 threads: t<128 -> column t of W (writes y), t>=128 -> column t-128 of
// W_self (writes x2/out). Each thread keeps its weight row in 128 VGPRs and
// grid-strides over rows; x-row loads are wave-uniform (scalar broadcast).
// ---------------------------------------------------------------------------
__global__ __launch_bounds__(256) void gemm_dual(
    const float* __restrict__ x,
    const float* __restrict__ W,  const float* __restrict__ bW,
    const float* __restrict__ Ws, const float* __restrict__ bs,
    float* __restrict__ y, float* __restrict__ x2, int N)
{
    const int t = threadIdx.x;
    const int m = t >> 7;           // 0: W, 1: W_self
    const int c = t & 127;
    const float* Wm = m ? Ws : W;
    float* dst = m ? x2 : y;
    const float bias = m ? bs[c] : bW[c];

    float wreg[D];
#pragma unroll
    for (int k = 0; k < D; k += 4) {
        const float4 v = *(const float4*)(Wm + (size_t)c * D + k);
        wreg[k] = v.x; wreg[k+1] = v.y; wreg[k+2] = v.z; wreg[k+3] = v.w;
    }

    for (int r = blockIdx.x; r < N; r += gridDim.x) {
        const float* xr = x + (size_t)r * D;
        float a0 = 0.f, a1 = 0.f, a2 = 0.f, a3 = 0.f;
#pragma unroll
        for (int k = 0; k < D; k += 4) {
            const float4 xv = *(const float4*)(xr + k);   // wave-uniform addr
            a0 += xv.x * wreg[k];
            a1 += xv.y * wreg[k+1];
            a2 += xv.z * wreg[k+2];
            a3 += xv.w * wreg[k+3];
        }
        dst[(size_t)r * D + c] = (a0 + a1) + (a2 + a3) + bias;
    }
}

// ---------------------------------------------------------------------------
// CSR build: histogram -> 3-kernel exclusive scan -> cursor scatter
// ---------------------------------------------------------------------------
__global__ __launch_bounds__(256) void hist_kernel(
    const int* __restrict__ row, unsigned* __restrict__ cnt, int E)
{
    for (int e = blockIdx.x * blockDim.x + threadIdx.x; e < E;
         e += gridDim.x * blockDim.x)
        atomicAdd(&cnt[row[e]], 1u);
}

__global__ __launch_bounds__(256) void scan1_kernel(
    const unsigned* __restrict__ cnt, unsigned* __restrict__ chunkSum, int n)
{
    __shared__ unsigned s[256];
    const int b = blockIdx.x, t = threadIdx.x;
    const int base = b * SCAN_CHUNK + t * 4;
    unsigned tsum = 0;
#pragma unroll
    for (int i = 0; i < 4; ++i) {
        const int idx = base + i;
        if (idx < n) tsum += cnt[idx];
    }
    s[t] = tsum; __syncthreads();
    for (int off = 128; off > 0; off >>= 1) {
        if (t < off) s[t] += s[t + off];
        __syncthreads();
    }
    if (t == 0) chunkSum[b] = s[0];
}

__global__ void scan2_kernel(const unsigned* __restrict__ chunkSum,
                             unsigned* __restrict__ chunkBase, int nc)
{
    if (threadIdx.x == 0) {
        unsigned run = 0;
        for (int i = 0; i < nc; ++i) { chunkBase[i] = run; run += chunkSum[i]; }
    }
}

__global__ __launch_bounds__(256) void scan3_kernel(
    const unsigned* __restrict__ cnt, const unsigned* __restrict__ chunkBase,
    unsigned* __restrict__ rowStart, unsigned* __restrict__ cursor, int n)
{
    __shared__ unsigned s[256];
    const int b = blockIdx.x, t = threadIdx.x;
    const int base = b * SCAN_CHUNK + t * 4;
    unsigned v[4];
    unsigned tsum = 0;
#pragma unroll
    for (int i = 0; i < 4; ++i) {
        const int idx = base + i;
        v[i] = (idx < n) ? cnt[idx] : 0u;
        tsum += v[i];
    }
    s[t] = tsum; __syncthreads();
    // Hillis-Steele inclusive scan of per-thread sums
    for (int off = 1; off < 256; off <<= 1) {
        unsigned u = (t >= off) ? s[t - off] : 0u;
        __syncthreads();
        s[t] += u;
        __syncthreads();
    }
    unsigned start = chunkBase[b] + (s[t] - tsum);
#pragma unroll
    for (int i = 0; i < 4; ++i) {
        const int idx = base + i;
        if (idx < n) { rowStart[idx] = start; cursor[idx] = start; }
        start += v[i];
    }
}

__global__ __launch_bounds__(256) void scatter_kernel(
    const int* __restrict__ row, const int* __restrict__ col,
    const float* __restrict__ val, unsigned* __restrict__ cursor,
    int* __restrict__ scol, float* __restrict__ sval, int E)
{
    for (int e = blockIdx.x * blockDim.x + threadIdx.x; e < E;
         e += gridDim.x * blockDim.x) {
        const int r = row[e];
        const unsigned p = atomicAdd(&cursor[r], 1u);
        scol[p] = col[e];
        sval[p] = val[e];
    }
}

// ---------------------------------------------------------------------------
// K3: one wave per row: agg[r] = sum_e val * y[col], out = relu(agg + x2)
// x2 already sits in d_out; lane l owns feature dims {2l, 2l+1}.
// ---------------------------------------------------------------------------
__global__ __launch_bounds__(256) void aggregate_kernel(
    const float* __restrict__ y, const int* __restrict__ scol,
    const float* __restrict__ sval, const unsigned* __restrict__ rowStart,
    float* __restrict__ out, int N, int E)
{
    const int w = (int)((blockIdx.x * blockDim.x + threadIdx.x) >> 6);
    const int lane = threadIdx.x & 63;
    const int nw = (int)((gridDim.x * blockDim.x) >> 6);

    for (int r = w; r < N; r += nw) {
        const unsigned s0 = rowStart[r];
        const unsigned e1 = (r + 1 < N) ? rowStart[r + 1] : (unsigned)E;
        float ax = 0.f, ay = 0.f;
        for (unsigned e = s0; e < e1; ++e) {
            const int   c = scol[e];           // wave-uniform
            const float v = sval[e];           // wave-uniform
            const float2 yv = *(const float2*)(y + (size_t)c * D + lane * 2);
            ax += v * yv.x;
            ay += v * yv.y;
        }
        float2 x2v = *(const float2*)(out + (size_t)r * D + lane * 2);
        float ox = ax + x2v.x, oy = ay + x2v.y;
        ox = ox > 0.f ? ox : 0.f;
        oy = oy > 0.f ? oy : 0.f;
        *(float2*)(out + (size_t)r * D + lane * 2) = make_float2(ox, oy);
    }
}

// ---------------------------------------------------------------------------
extern "C" void kernel_launch(void* const* d_in, const int* in_sizes, int n_in,
                              void* d_out, int out_size, void* d_ws, size_t ws_size,
                              hipStream_t stream)
{
    const float* x        = (const float*)d_in[0];
    const int*   edge_row = (const int*)  d_in[1];
    const int*   edge_col = (const int*)  d_in[2];
    const float* edge_val = (const float*)d_in[3];
    const float* W        = (const float*)d_in[4];
    const float* bW       = (const float*)d_in[5];
    const float* Ws       = (const float*)d_in[6];
    const float* bs       = (const float*)d_in[7];
    float* out = (float*)d_out;

    const int N = in_sizes[0] / D;      // 100000
    const int E = in_sizes[1];          // 3200000
    const int NCHUNK = (N + SCAN_CHUNK - 1) / SCAN_CHUNK;   // 98

    // workspace layout
    float*    y         = (float*)d_ws;                 // N*D floats
    unsigned* cnt       = (unsigned*)(y + (size_t)N * D);
    unsigned* rowStart  = cnt + N;
    unsigned* cursor    = rowStart + N;
    unsigned* chunkSum  = cursor + N;                   // NCHUNK (<=128)
    unsigned* chunkBase = chunkSum + 128;
    int*      scol      = (int*)(chunkBase + 128);      // E
    float*    sval      = (float*)(scol + E);           // E

    // dense part: y into ws, x2 into out
    hipLaunchKernelGGL(gemm_dual, dim3(1024), dim3(256), 0, stream,
                       x, W, bW, Ws, bs, y, out, N);

    // CSR build
    hipMemsetAsync(cnt, 0, (size_t)N * sizeof(unsigned), stream);
    hipLaunchKernelGGL(hist_kernel, dim3(2048), dim3(256), 0, stream,
                       edge_row, cnt, E);
    hipLaunchKernelGGL(scan1_kernel, dim3(NCHUNK), dim3(256), 0, stream,
                       cnt, chunkSum, N);
    hipLaunchKernelGGL(scan2_kernel, dim3(1), dim3(64), 0, stream,
                       chunkSum, chunkBase, NCHUNK);
    hipLaunchKernelGGL(scan3_kernel, dim3(NCHUNK), dim3(256), 0, stream,
                       cnt, chunkBase, rowStart, cursor, N);
    hipLaunchKernelGGL(scatter_kernel, dim3(2048), dim3(256), 0, stream,
                       edge_row, edge_col, edge_val, cursor, scol, sval, E);

    // pull aggregation + x2 + relu, writes d_out
    hipLaunchKernelGGL(aggregate_kernel, dim3(4096), dim3(256), 0, stream,
                       y, scol, sval, rowStart, out, N, E);
}

// Round 5
// 691.191 us; speedup vs baseline: 1.5633x; 1.5633x over previous
//
#include <hip/hip_runtime.h>
#include <hip/hip_bf16.h>

#define D 128
#define SCAN_CHUNK 1024

typedef __attribute__((ext_vector_type(8))) short short8v;
typedef __attribute__((ext_vector_type(4))) float floatx4;

__device__ inline short f2bf(float f) {
    union { float f; unsigned u; } v; v.f = f;
    unsigned r = v.u + 0x7fffu + ((v.u >> 16) & 1u);   // RNE
    return (short)(r >> 16);
}
__device__ inline float bf2f(short h) {
    union { unsigned u; float f; } v;
    v.u = ((unsigned)(unsigned short)h) << 16;
    return v.f;
}

// ---------------------------------------------------------------------------
// W convert: Whb[0..127][k]=W, Whb[128..255][k]=Ws  (bf16 bits as short)
// ---------------------------------------------------------------------------
__global__ __launch_bounds__(256) void convert_w(
    const float* __restrict__ W, const float* __restrict__ Ws,
    short* __restrict__ Whb)
{
    const int i = blockIdx.x * 256 + threadIdx.x;
    if (i < D * D) {
        Whb[i] = f2bf(W[i]);
        Whb[D * D + i] = f2bf(Ws[i]);
    }
}

// ---------------------------------------------------------------------------
// MFMA GEMM: per block 64 rows x 256 cols (cols 0-127 -> yh bf16,
// 128-255 -> x2 f32 into d_out). 4 waves, each 16 rows.
// A frag: lane holds x[r0+(l&15)][kc*32+(l>>4)*8 +0..7]  (cvt f32->bf16)
// B frag: lane holds Whb[ct*16+(l&15)][kc*32+(l>>4)*8 +0..7]
// D frag: D[(l>>4)*4+r][l&15]
// ---------------------------------------------------------------------------
__global__ __launch_bounds__(256) void gemm_mfma(
    const float* __restrict__ x, const short* __restrict__ Whb,
    const float* __restrict__ bW, const float* __restrict__ bs,
    short* __restrict__ yh, float* __restrict__ out, int N)
{
    const int l  = threadIdx.x & 63;
    const int w  = threadIdx.x >> 6;
    const int r0 = blockIdx.x * 64 + w * 16;
    const int lr = l & 15;
    const int lk = l >> 4;

    const int arow = r0 + lr;
    const int arow_c = arow < N ? arow : N - 1;
    const float* xr = x + (size_t)arow_c * D;

    short8v afrag[4];
#pragma unroll
    for (int kc = 0; kc < 4; ++kc) {
        const float4 f0 = *(const float4*)(xr + kc * 32 + lk * 8);
        const float4 f1 = *(const float4*)(xr + kc * 32 + lk * 8 + 4);
        short8v a;
        a[0] = f2bf(f0.x); a[1] = f2bf(f0.y); a[2] = f2bf(f0.z); a[3] = f2bf(f0.w);
        a[4] = f2bf(f1.x); a[5] = f2bf(f1.y); a[6] = f2bf(f1.z); a[7] = f2bf(f1.w);
        afrag[kc] = a;
    }

#pragma unroll
    for (int ct = 0; ct < 16; ++ct) {
        const short* wrow = Whb + (size_t)(ct * 16 + lr) * D;
        floatx4 acc = {0.f, 0.f, 0.f, 0.f};
#pragma unroll
        for (int kc = 0; kc < 4; ++kc) {
            const short8v b = *(const short8v*)(wrow + kc * 32 + lk * 8);
            acc = __builtin_amdgcn_mfma_f32_16x16x32_bf16(afrag[kc], b, acc, 0, 0, 0);
        }
        const int col  = (ct & 7) * 16 + lr;          // 0..127 within its output
        const float bias = (ct < 8) ? bW[col] : bs[col];
#pragma unroll
        for (int r = 0; r < 4; ++r) {
            const int row = r0 + lk * 4 + r;
            if (row < N) {
                if (ct < 8) yh[(size_t)row * D + col] = f2bf(acc[r] + bias);
                else        out[(size_t)row * D + col] = acc[r] + bias;
            }
        }
    }
}

// ---------------------------------------------------------------------------
// CSR build: histogram -> scan -> cursor scatter (packed int2{col,val_bits})
// ---------------------------------------------------------------------------
__global__ __launch_bounds__(256) void hist_kernel(
    const int* __restrict__ row, unsigned* __restrict__ cnt, int E)
{
    for (int e = blockIdx.x * blockDim.x + threadIdx.x; e < E;
         e += gridDim.x * blockDim.x)
        atomicAdd(&cnt[row[e]], 1u);
}

__global__ __launch_bounds__(256) void scan1_kernel(
    const unsigned* __restrict__ cnt, unsigned* __restrict__ chunkSum, int n)
{
    __shared__ unsigned s[256];
    const int b = blockIdx.x, t = threadIdx.x;
    const int base = b * SCAN_CHUNK + t * 4;
    unsigned tsum = 0;
#pragma unroll
    for (int i = 0; i < 4; ++i) {
        const int idx = base + i;
        if (idx < n) tsum += cnt[idx];
    }
    s[t] = tsum; __syncthreads();
    for (int off = 128; off > 0; off >>= 1) {
        if (t < off) s[t] += s[t + off];
        __syncthreads();
    }
    if (t == 0) chunkSum[b] = s[0];
}

__global__ __launch_bounds__(128) void scan2_kernel(
    const unsigned* __restrict__ chunkSum, unsigned* __restrict__ chunkBase, int nc)
{
    __shared__ unsigned s[128];
    const int t = threadIdx.x;
    const unsigned v = (t < nc) ? chunkSum[t] : 0u;
    s[t] = v; __syncthreads();
    for (int off = 1; off < 128; off <<= 1) {
        const unsigned u = (t >= off) ? s[t - off] : 0u;
        __syncthreads();
        s[t] += u;
        __syncthreads();
    }
    if (t < nc) chunkBase[t] = s[t] - v;   // exclusive
}

__global__ __launch_bounds__(256) void scan3_kernel(
    const unsigned* __restrict__ cnt, const unsigned* __restrict__ chunkBase,
    unsigned* __restrict__ rowStart, unsigned* __restrict__ cursor, int n)
{
    __shared__ unsigned s[256];
    const int b = blockIdx.x, t = threadIdx.x;
    const int base = b * SCAN_CHUNK + t * 4;
    unsigned v[4];
    unsigned tsum = 0;
#pragma unroll
    for (int i = 0; i < 4; ++i) {
        const int idx = base + i;
        v[i] = (idx < n) ? cnt[idx] : 0u;
        tsum += v[i];
    }
    s[t] = tsum; __syncthreads();
    for (int off = 1; off < 256; off <<= 1) {
        const unsigned u = (t >= off) ? s[t - off] : 0u;
        __syncthreads();
        s[t] += u;
        __syncthreads();
    }
    unsigned start = chunkBase[b] + (s[t] - tsum);
#pragma unroll
    for (int i = 0; i < 4; ++i) {
        const int idx = base + i;
        if (idx < n) { rowStart[idx] = start; cursor[idx] = start; }
        start += v[i];
    }
}

__global__ __launch_bounds__(256) void scatter_kernel(
    const int* __restrict__ row, const int* __restrict__ col,
    const float* __restrict__ val, unsigned* __restrict__ cursor,
    int2* __restrict__ pack, int E)
{
    for (int e = blockIdx.x * blockDim.x + threadIdx.x; e < E;
         e += gridDim.x * blockDim.x) {
        const int r = row[e];
        const unsigned p = atomicAdd(&cursor[r], 1u);
        pack[p] = make_int2(col[e], __float_as_int(val[e]));
    }
}

// ---------------------------------------------------------------------------
// Pull aggregation: one wave per row, 4 edges per iteration.
// lane = g*16 + fl:  g = edge slot (0..3), fl = feature block (8 bf16 = 16B).
// Cross-group reduce via shfl_xor(16), shfl_xor(32); g==0 lanes do epilogue.
// ---------------------------------------------------------------------------
__global__ __launch_bounds__(256) void aggregate_kernel(
    const short* __restrict__ yh, const int2* __restrict__ pack,
    const unsigned* __restrict__ rowStart,
    float* __restrict__ out, int N, int E)
{
    const int wid = (int)((blockIdx.x * blockDim.x + threadIdx.x) >> 6);
    const int nw  = (int)((gridDim.x * blockDim.x) >> 6);
    const int l   = threadIdx.x & 63;
    const int g   = l >> 4;
    const int fl  = l & 15;

    for (int r = wid; r < N; r += nw) {
        const unsigned s0 = rowStart[r];
        const unsigned e1 = (r + 1 < N) ? rowStart[r + 1] : (unsigned)E;
        float acc[8] = {0.f, 0.f, 0.f, 0.f, 0.f, 0.f, 0.f, 0.f};

        unsigned e = s0;
        for (; e + 4 <= e1; e += 4) {
            const int2 p = pack[e + g];
            const float v = __int_as_float(p.y);
            const short8v yv = *(const short8v*)(yh + (size_t)p.x * D + fl * 8);
#pragma unroll
            for (int j = 0; j < 8; ++j) acc[j] += v * bf2f(yv[j]);
        }
        if (e < e1) {                       // tail: 1..3 edges, slot-masked
            const unsigned idx = e + (unsigned)g;
            const bool act = idx < e1;
            int2 p = make_int2(0, 0);
            if (act) p = pack[idx];
            const float v = act ? __int_as_float(p.y) : 0.f;
            const short8v yv = *(const short8v*)(yh + (size_t)p.x * D + fl * 8);
#pragma unroll
            for (int j = 0; j < 8; ++j) acc[j] += v * bf2f(yv[j]);
        }

#pragma unroll
        for (int j = 0; j < 8; ++j) {
            acc[j] += __shfl_xor(acc[j], 16, 64);
            acc[j] += __shfl_xor(acc[j], 32, 64);
        }

        if (g == 0) {
            float* op = out + (size_t)r * D + fl * 8;
            const float4 x0 = *(const float4*)(op);
            const float4 x1 = *(const float4*)(op + 4);
            float4 o0, o1;
            o0.x = acc[0] + x0.x; o0.y = acc[1] + x0.y;
            o0.z = acc[2] + x0.z; o0.w = acc[3] + x0.w;
            o1.x = acc[4] + x1.x; o1.y = acc[5] + x1.y;
            o1.z = acc[6] + x1.z; o1.w = acc[7] + x1.w;
            o0.x = o0.x > 0.f ? o0.x : 0.f;  o0.y = o0.y > 0.f ? o0.y : 0.f;
            o0.z = o0.z > 0.f ? o0.z : 0.f;  o0.w = o0.w > 0.f ? o0.w : 0.f;
            o1.x = o1.x > 0.f ? o1.x : 0.f;  o1.y = o1.y > 0.f ? o1.y : 0.f;
            o1.z = o1.z > 0.f ? o1.z : 0.f;  o1.w = o1.w > 0.f ? o1.w : 0.f;
            *(float4*)(op)     = o0;
            *(float4*)(op + 4) = o1;
        }
    }
}

// ---------------------------------------------------------------------------
extern "C" void kernel_launch(void* const* d_in, const int* in_sizes, int n_in,
                              void* d_out, int out_size, void* d_ws, size_t ws_size,
                              hipStream_t stream)
{
    const float* x        = (const float*)d_in[0];
    const int*   edge_row = (const int*)  d_in[1];
    const int*   edge_col = (const int*)  d_in[2];
    const float* edge_val = (const float*)d_in[3];
    const float* W        = (const float*)d_in[4];
    const float* bW       = (const float*)d_in[5];
    const float* Ws       = (const float*)d_in[6];
    const float* bs       = (const float*)d_in[7];
    float* out = (float*)d_out;

    const int N = in_sizes[0] / D;      // 100000
    const int E = in_sizes[1];          // 3200000
    const int NCHUNK = (N + SCAN_CHUNK - 1) / SCAN_CHUNK;   // 98

    // workspace layout
    short*    yh        = (short*)d_ws;                       // N*D bf16
    short*    Whb       = yh + (size_t)N * D;                 // 2*D*D bf16
    unsigned* cnt       = (unsigned*)(Whb + 2 * D * D);
    unsigned* rowStart  = cnt + N;
    unsigned* cursor    = rowStart + N;
    unsigned* chunkSum  = cursor + N;                         // 128
    unsigned* chunkBase = chunkSum + 128;                     // 128
    int2*     pack      = (int2*)(chunkBase + 128);           // E

    hipLaunchKernelGGL(convert_w, dim3((D * D + 255) / 256), dim3(256), 0, stream,
                       W, Ws, Whb);
    hipLaunchKernelGGL(gemm_mfma, dim3((N + 63) / 64), dim3(256), 0, stream,
                       x, Whb, bW, bs, yh, out, N);

    hipMemsetAsync(cnt, 0, (size_t)N * sizeof(unsigned), stream);
    hipLaunchKernelGGL(hist_kernel, dim3(2048), dim3(256), 0, stream,
                       edge_row, cnt, E);
    hipLaunchKernelGGL(scan1_kernel, dim3(NCHUNK), dim3(256), 0, stream,
                       cnt, chunkSum, N);
    hipLaunchKernelGGL(scan2_kernel, dim3(1), dim3(128), 0, stream,
                       chunkSum, chunkBase, NCHUNK);
    hipLaunchKernelGGL(scan3_kernel, dim3(NCHUNK), dim3(256), 0, stream,
                       cnt, chunkBase, rowStart, cursor, N);
    hipLaunchKernelGGL(scatter_kernel, dim3(2048), dim3(256), 0, stream,
                       edge_row, edge_col, edge_val, cursor, pack, E);

    hipLaunchKernelGGL(aggregate_kernel, dim3(4096), dim3(256), 0, stream,
                       yh, pack, rowStart, out, N, E);
}